// Round 5
// baseline (6839.967 us; speedup 1.0000x reference)
//
#include <hip/hip_runtime.h>
#include <hip/hip_bf16.h>
#include <math.h>

#define B_ 128
#define T_ 2048
#define D_ 256
#define U_ 512
#define G4_ 2048
#define KT_ 768            // 512 (recurrent) + 256 (input) k-rows, transposed layout
#define ALPHA_ 0.001f

#define NGROUP 8           // batch groups (one per XCD)
#define GB 16              // samples per group
#define NSLICE 16          // u-slices per group
#define SU 32              // u per slice
#define NWG (NGROUP*NSLICE) // 128
#define NTH 256
#define BU (B_*U_)

typedef __attribute__((ext_vector_type(8))) short bf16x8;
typedef __attribute__((ext_vector_type(4))) float f32x4;
typedef __attribute__((ext_vector_type(4))) int i32x4;
typedef __attribute__((ext_vector_type(2))) int i32x2;
typedef __attribute__((ext_vector_type(4))) unsigned short us4;

// workspace layout (bytes)
#define OFF_WT 0                        // transposed bf16 weights: G4_*KT_*2 = 3 MiB
#define OFF_H32 (G4_*KT_*2)             // 2 tagged h buffers: 2*BU*4 = 512 KiB
#define OFF_FLG (OFF_H32 + 2*BU*4)      // flags: 8 groups x 64 dwords (256B apart)
#define FLG_DW (NGROUP*64)

__device__ __forceinline__ unsigned short f2b(float f) {
  unsigned u = __builtin_bit_cast(unsigned, f);
  u += 0x7fffu + ((u >> 16) & 1u);   // round-to-nearest-even bf16
  return (unsigned short)(u >> 16);
}

__device__ __forceinline__ float ftanh(float v) {
  v = fminf(fmaxf(v, -15.f), 15.f);
  float e = __expf(2.f * v);
  return (e - 1.f) * __builtin_amdgcn_rcpf(e + 1.f);
}

__device__ __forceinline__ unsigned umin_(unsigned a, unsigned b) { return a < b ? a : b; }

__device__ __forceinline__ unsigned min16(i32x4 a, i32x4 b, i32x4 c, i32x4 d) {
  unsigned m0 = umin_(umin_((unsigned)a[0], (unsigned)a[1]), umin_((unsigned)a[2], (unsigned)a[3]));
  unsigned m1 = umin_(umin_((unsigned)b[0], (unsigned)b[1]), umin_((unsigned)b[2], (unsigned)b[3]));
  unsigned m2 = umin_(umin_((unsigned)c[0], (unsigned)c[1]), umin_((unsigned)c[2], (unsigned)c[3]));
  unsigned m3 = umin_(umin_((unsigned)d[0], (unsigned)d[1]), umin_((unsigned)d[2], (unsigned)d[3]));
  return umin_(umin_(m0, m1), umin_(m2, m3));
}

// weights transposed to [col][k] so fragment loads are contiguous 16B
__global__ void prep_kernel(const float* __restrict__ kern,
                            const float* __restrict__ rker,
                            const float* __restrict__ h0,
                            unsigned short* __restrict__ wt,
                            unsigned* __restrict__ h32,
                            unsigned* __restrict__ flg) {
  int idx = blockIdx.x * blockDim.x + threadIdx.x;
  int stride = gridDim.x * blockDim.x;
  for (int i = idx; i < G4_ * KT_; i += stride) {
    int col = i / KT_, k = i - col * KT_;
    float v = (k < U_) ? rker[(size_t)k * G4_ + col]
                       : kern[(size_t)(k - U_) * G4_ + col];
    wt[i] = f2b(v);
  }
  for (int i = idx; i < BU; i += stride) {
    h32[i] = ((unsigned)f2b(h0[i]) << 16);   // tag 0 = state entering step 0
    h32[BU + i] = 0xFFFFu;                   // impossible tag (clears stale runs)
  }
  for (int i = idx; i < FLG_DW; i += stride) flg[i] = 0u;
}

// coalesced bulk h load: per instruction, 64 lanes x 16B = 1KB contiguous
#define LOAD8()                                                        \
  asm volatile(                                                        \
      "global_load_dwordx4 %0, %8, off sc0 sc1\n\t"                    \
      "global_load_dwordx4 %1, %8, off offset:1024 sc0 sc1\n\t"        \
      "global_load_dwordx4 %2, %8, off offset:2048 sc0 sc1\n\t"        \
      "global_load_dwordx4 %3, %8, off offset:3072 sc0 sc1\n\t"        \
      "global_load_dwordx4 %4, %9, off sc0 sc1\n\t"                    \
      "global_load_dwordx4 %5, %9, off offset:1024 sc0 sc1\n\t"        \
      "global_load_dwordx4 %6, %9, off offset:2048 sc0 sc1\n\t"        \
      "global_load_dwordx4 %7, %9, off offset:3072 sc0 sc1"            \
      : "=&v"(v0), "=&v"(v1), "=&v"(v2), "=&v"(v3),                    \
        "=&v"(v4), "=&v"(v5), "=&v"(v6), "=&v"(v7)                     \
      : "v"(ppoll), "v"(ppoll2));                                      \
  __builtin_amdgcn_sched_barrier(0)

#define FENCE8()                                                       \
  asm volatile("s_waitcnt vmcnt(0)"                                    \
      : "+v"(v0), "+v"(v1), "+v"(v2), "+v"(v3),                        \
        "+v"(v4), "+v"(v5), "+v"(v6), "+v"(v7));                       \
  __builtin_amdgcn_sched_barrier(0)

// flag poll: 16 dwords (one 64B line), uniform address across lanes
#define LOADF(a,b,c,d)                                                 \
  asm volatile(                                                        \
      "global_load_dwordx4 %0, %4, off sc0 sc1\n\t"                    \
      "global_load_dwordx4 %1, %4, off offset:16 sc0 sc1\n\t"          \
      "global_load_dwordx4 %2, %4, off offset:32 sc0 sc1\n\t"          \
      "global_load_dwordx4 %3, %4, off offset:48 sc0 sc1"              \
      : "=&v"(a), "=&v"(b), "=&v"(c), "=&v"(d)                         \
      : "v"(pflag));                                                    \
  __builtin_amdgcn_sched_barrier(0)

#define WAITSET(a,b,c,d)                                               \
  asm volatile("s_waitcnt vmcnt(4)"                                    \
      : "+v"(a), "+v"(b), "+v"(c), "+v"(d));                           \
  __builtin_amdgcn_sched_barrier(0)

#define CKV(vv) ((((unsigned)(vv)[0] ^ tgv) & 0xffffu) |               \
                 (((unsigned)(vv)[1] ^ tgv) & 0xffffu) |               \
                 (((unsigned)(vv)[2] ^ tgv) & 0xffffu) |               \
                 (((unsigned)(vv)[3] ^ tgv) & 0xffffu))

#define PK(lo, hi) (int)(((unsigned)(hi) & 0xffff0000u) | ((unsigned)(lo) >> 16))

// strip tags from one 16B chunk -> 8B bf16 pair-write to swizzled LDS
#define PACK2(vv, k)                                                         \
  { const int r_ = 4 * wv + ((k) >> 1);                                      \
    const int ba_ = (r_ * 1024 + (((k) & 1) << 9) + 8 * ln) ^ ((r_ & 7) << 4); \
    i32x2 d_ = { PK((vv)[0], (vv)[1]), PK((vv)[2], (vv)[3]) };               \
    *(i32x2*)(hdst + ba_) = d_; }

__global__ __launch_bounds__(NTH, 1) void plstm_kernel(
    const float* __restrict__ x, const float* __restrict__ h0,
    const float* __restrict__ c0, const float* __restrict__ t0,
    const float* __restrict__ bias, const float* __restrict__ tg,
    const unsigned short* __restrict__ wt,
    unsigned* h32, unsigned* flg, float* __restrict__ out) {
  const int wg = blockIdx.x;
  const int g = wg & 7, sl = wg >> 3;   // group == XCD (round-robin dispatch)
  const int b0 = g * GB, u0 = sl * SU;
  const int tid = threadIdx.x;
  const int wave = tid >> 6, lane = tid & 63;

  __shared__ unsigned short h_lds[2][GB * U_];   // 2 x 16 KiB
  __shared__ unsigned short x_lds[2][GB * D_];   // 2 x 8 KiB
  __shared__ float z_lds[2][GB][130];            // pad -> conflict-free

  // ---- weight fragments (transposed layout: contiguous 16B per frag) ----
  bf16x8 br0[16], br1[16], bx0[8], bx1[8];
  {
    const int kr0 = (lane >> 4) * 8;
    const int col0 = wave * U_ + u0 + (lane & 15);
    const unsigned short* w0 = wt + (size_t)col0 * KT_;
    const unsigned short* w1 = wt + (size_t)(col0 + 16) * KT_;
#pragma unroll
    for (int kt = 0; kt < 16; ++kt) {
      br0[kt] = *(const bf16x8*)(w0 + kt * 32 + kr0);
      br1[kt] = *(const bf16x8*)(w1 + kt * 32 + kr0);
    }
#pragma unroll
    for (int kt = 0; kt < 8; ++kt) {
      bx0[kt] = *(const bf16x8*)(w0 + U_ + kt * 32 + kr0);
      bx1[kt] = *(const bf16x8*)(w1 + U_ + kt * 32 + kr0);
    }
  }
  const float bias0 = bias[wave * U_ + u0 + (lane & 15)];
  const float bias1 = bias[wave * U_ + u0 + 16 + (lane & 15)];

  // ---- per-thread elementwise state: sample=row, u = u0+2*chunk (+1) ----
  const int row = tid >> 4;
  const int chunk = tid & 15;
  const int bb = b0 + row;
  const int ua = u0 + 2 * chunk, ub = ua + 1;
  float c_a = c0[bb * U_ + ua], c_b = c0[bb * U_ + ub];
  float h_a = h0[bb * U_ + ua], h_b = h0[bb * U_ + ub];
  const float t0a = t0[bb * U_ + ua], t0b = t0[bb * U_ + ub];
  const float per_a = tg[ua], per_b = tg[ub];
  const float sh_a = tg[U_ + ua], sh_b = tg[U_ + ub];
  const float ro_a = tg[2 * U_ + ua], ro_b = tg[2 * U_ + ub];

  const int arow = lane & 15;
  const int koff = (lane >> 4) * 16;
  const int swzA = (arow & 7) << 4;
  const int swzR = (row & 7) << 4;
  const int wv = wave, ln = lane;

  auto stage_x = [&](int t, int buf) {
    const int f0 = chunk * 16;
    const float* xp = x + ((size_t)bb * T_ + t) * D_ + f0;
    char* base = (char*)&x_lds[buf][0];
#pragma unroll
    for (int q = 0; q < 4; ++q) {
      float4 v = *(const float4*)(xp + q * 4);
      us4 pk = { f2b(v.x), f2b(v.y), f2b(v.z), f2b(v.w) };
      *(us4*)(base + ((row * 512 + (f0 + q * 4) * 2) ^ swzR)) = pk;
    }
  };

  stage_x(0, 0);
  stage_x(1, 1);
  __syncthreads();

  // wave-linear poll pointers: wave w covers group-slab bytes [w*8K, (w+1)*8K)
  const unsigned* gslab0 = h32 + (size_t)b0 * U_;
  const int poff = wv * 2048 + ln * 4;   // dwords
  const unsigned* pflag = flg + g * 64;  // 16 producer flags, one 64B line

  for (int step = 0; step < T_; ++step) {
    const int par = step & 1;

    // ---- (0) time-gate coefficients for this step (poll-shadow VALU) ----
    float kka, kkb;
    {
      const float s1f = (float)(step + 1);
      float xx = t0a + s1f - sh_a;
      float fl = floorf(xx / per_a);
      float ph = (xx - per_a * fl) / per_a;
      kka = (ph <= 0.5f * ro_a) ? (2.f * ph / ro_a)
          : ((ph <= ro_a) ? (2.f - 2.f * ph / ro_a) : (ALPHA_ * ph));
      xx = t0b + s1f - sh_b;
      fl = floorf(xx / per_b);
      ph = (xx - per_b * fl) / per_b;
      kkb = (ph <= 0.5f * ro_b) ? (2.f * ph / ro_b)
          : ((ph <= ro_b) ? (2.f - 2.f * ph / ro_b) : (ALPHA_ * ph));
    }

    // ---- (1) flag set A in flight ----
    i32x4 fa0, fa1, fa2, fa3, fb0, fb1, fb2, fb3;
    LOADF(fa0, fa1, fa2, fa3);

    // ---- (2) x-partial GEMM (creates ~250cy skew between flag sets) ----
    f32x4 a0a = { bias0, bias0, bias0, bias0 };
    f32x4 a1a = { bias1, bias1, bias1, bias1 };
    f32x4 a0b = { 0.f, 0.f, 0.f, 0.f };
    f32x4 a1b = { 0.f, 0.f, 0.f, 0.f };
    {
      const char* xb = (const char*)&x_lds[par][0];
#pragma unroll
      for (int kt = 0; kt < 8; ++kt) {
        bf16x8 a = *(const bf16x8*)(xb + ((arow * 512 + kt * 64 + koff) ^ swzA));
        if (kt & 1) {
          a0b = __builtin_amdgcn_mfma_f32_16x16x32_bf16(a, bx0[kt], a0b, 0, 0, 0);
          a1b = __builtin_amdgcn_mfma_f32_16x16x32_bf16(a, bx1[kt], a1b, 0, 0, 0);
        } else {
          a0a = __builtin_amdgcn_mfma_f32_16x16x32_bf16(a, bx0[kt], a0a, 0, 0, 0);
          a1a = __builtin_amdgcn_mfma_f32_16x16x32_bf16(a, bx1[kt], a1a, 0, 0, 0);
        }
      }
    }

    // ---- (3) staggered flag poll: sampling period ~= RTT/2 ----
    const unsigned tgt = (unsigned)step;
    LOADF(fb0, fb1, fb2, fb3);
    for (;;) {
      WAITSET(fa0, fa1, fa2, fa3);
      if (min16(fa0, fa1, fa2, fa3) >= tgt) break;
      LOADF(fa0, fa1, fa2, fa3);
      WAITSET(fb0, fb1, fb2, fb3);
      if (min16(fb0, fb1, fb2, fb3) >= tgt) break;
      LOADF(fb0, fb1, fb2, fb3);
    }

    // ---- (4) bulk tagged-h load, verified (passes ~always) ----
    const unsigned* ppoll = gslab0 + (size_t)par * BU + poff;
    const unsigned* ppoll2 = ppoll + 1024;
    i32x4 v0, v1, v2, v3, v4, v5, v6, v7;
    LOAD8();
    FENCE8();   // vmcnt(0): h loads + all flag stragglers retired
    asm volatile("" :: "v"(fa0), "v"(fa1), "v"(fa2), "v"(fa3),
                       "v"(fb0), "v"(fb1), "v"(fb2), "v"(fb3));
    const unsigned tgv = tgt;
    for (;;) {
      unsigned bad = CKV(v0) | CKV(v1) | CKV(v2) | CKV(v3) |
                     CKV(v4) | CKV(v5) | CKV(v6) | CKV(v7);
      if (!bad) break;
      __builtin_amdgcn_s_sleep(1);
      LOAD8();
      FENCE8();
    }

    // ---- (5) strip tags -> swizzled h_lds[par] (8B writes, conflict-free) ----
    {
      char* hdst = (char*)&h_lds[par][0];
      PACK2(v0, 0); PACK2(v1, 1); PACK2(v2, 2); PACK2(v3, 3);
      PACK2(v4, 4); PACK2(v5, 5); PACK2(v6, 6); PACK2(v7, 7);
    }
    __syncthreads();   // S1: h_lds[par] ready

    // ---- (6) recurrent GEMM (4 interleaved acc chains -> issue-bound) ----
    {
      const char* hbm = (const char*)&h_lds[par][0];
#pragma unroll
      for (int kt = 0; kt < 16; ++kt) {
        bf16x8 a = *(const bf16x8*)(hbm + ((arow * 1024 + kt * 64 + koff) ^ swzA));
        if (kt & 1) {
          a0b = __builtin_amdgcn_mfma_f32_16x16x32_bf16(a, br0[kt], a0b, 0, 0, 0);
          a1b = __builtin_amdgcn_mfma_f32_16x16x32_bf16(a, br1[kt], a1b, 0, 0, 0);
        } else {
          a0a = __builtin_amdgcn_mfma_f32_16x16x32_bf16(a, br0[kt], a0a, 0, 0, 0);
          a1a = __builtin_amdgcn_mfma_f32_16x16x32_bf16(a, br1[kt], a1a, 0, 0, 0);
        }
      }
    }
    const f32x4 acc0 = a0a + a0b;
    const f32x4 acc1 = a1a + a1b;

    // ---- (7) z exchange (C/D: col=lane&15, row=(lane>>4)*4+r) ----
#pragma unroll
    for (int r2 = 0; r2 < 4; ++r2) {
      z_lds[par][(lane >> 4) * 4 + r2][wave * 32 + (lane & 15)] = acc0[r2];
      z_lds[par][(lane >> 4) * 4 + r2][wave * 32 + 16 + (lane & 15)] = acc1[r2];
    }
    __syncthreads();   // S2: z ready

    // ---- (8) gates: h first -> tagged store + flag ASAP, then c/out ----
    {
      const float* zr = &z_lds[par][row][0];
      const int c2 = 2 * chunk;
      const float zi_a = zr[c2],      zi_b = zr[c2 + 1];
      const float zf_a = zr[32 + c2], zf_b = zr[33 + c2];
      const float zc_a = zr[64 + c2], zc_b = zr[65 + c2];
      const float zo_a = zr[96 + c2], zo_b = zr[97 + c2];

      float ig_a = fminf(fmaxf(0.2f * zi_a + 0.5f, 0.f), 1.f);
      float fg_a = fminf(fmaxf(0.2f * zf_a + 0.5f, 0.f), 1.f);
      float og_a = fminf(fmaxf(0.2f * zo_a + 0.5f, 0.f), 1.f);
      float chat_a = fg_a * c_a + ig_a * ftanh(zc_a);
      float hhat_a = og_a * ftanh(chat_a);
      h_a = kka * hhat_a + (1.f - kka) * h_a;

      float ig_b = fminf(fmaxf(0.2f * zi_b + 0.5f, 0.f), 1.f);
      float fg_b = fminf(fmaxf(0.2f * zf_b + 0.5f, 0.f), 1.f);
      float og_b = fminf(fmaxf(0.2f * zo_b + 0.5f, 0.f), 1.f);
      float chat_b = fg_b * c_b + ig_b * ftanh(zc_b);
      float hhat_b = og_b * ftanh(chat_b);
      h_b = kkb * hhat_b + (1.f - kkb) * h_b;

      // tagged h broadcast (critical path) — one 8B L2-bypass store
      {
        unsigned* hn = h32 + (size_t)((step + 1) & 1) * BU + bb * U_;
        const unsigned tagn = (unsigned)(step + 1);
        i32x2 hv = { (int)(((unsigned)f2b(h_a) << 16) | tagn),
                     (int)(((unsigned)f2b(h_b) << 16) | tagn) };
        const unsigned* hp = hn + ua;
        asm volatile("global_store_dwordx2 %0, %1, off sc0 sc1"
                     :: "v"(hp), "v"(hv) : "memory");
      }
      if (tid == 0) {
        unsigned fv = (unsigned)(step + 1);
        const unsigned* fp = flg + g * 64 + sl;
        asm volatile("global_store_dword %0, %1, off sc0 sc1"
                     :: "v"(fp), "v"(fv) : "memory");
      }

      // off-critical-path tail
      c_a = kka * chat_a + (1.f - kka) * c_a;
      c_b = kkb * chat_b + (1.f - kkb) * c_b;
      float2 ov; ov.x = h_a; ov.y = h_b;
      *(float2*)(out + ((size_t)bb * T_ + step) * U_ + ua) = ov;
    }

    // ---- (9) x prefetch in the slack window ----
    if (step + 2 < T_) stage_x(step + 2, par);
  }
}

extern "C" void kernel_launch(void* const* d_in, const int* in_sizes, int n_in,
                              void* d_out, int out_size, void* d_ws,
                              size_t ws_size, hipStream_t stream) {
  const float* x    = (const float*)d_in[0];
  const float* h0   = (const float*)d_in[1];
  const float* c0   = (const float*)d_in[2];
  const float* t0   = (const float*)d_in[3];
  const float* kern = (const float*)d_in[4];
  const float* rker = (const float*)d_in[5];
  const float* bias = (const float*)d_in[6];
  const float* tg   = (const float*)d_in[7];
  float* out = (float*)d_out;

  char* ws = (char*)d_ws;
  unsigned short* wt = (unsigned short*)(ws + OFF_WT);
  unsigned* h32      = (unsigned*)(ws + OFF_H32);
  unsigned* flags    = (unsigned*)(ws + OFF_FLG);

  prep_kernel<<<1024, 256, 0, stream>>>(kern, rker, h0, wt, h32, flags);
  plstm_kernel<<<NWG, NTH, 0, stream>>>(x, h0, c0, t0, bias, tg, wt, h32,
                                        flags, out);
}